// Round 6
// baseline (286.500 us; speedup 1.0000x reference)
//
#include <hip/hip_runtime.h>
#include <hip/hip_fp16.h>

#define N_IN   128
#define HID    32
#define ODIM   12
#define H2P    16           // padded h2 row: 16 halves = 32 B aligned
#define RNODES 128          // nodes per coarse bucket (dst >> 7)
#define RSH    7
#define NBMAX  800          // >= ceil(100000/128) = 782
#define NBK    1024         // bucket counter count (pow2)
#define BCAP   4608         // coarse bucket capacity; mean 4096, ~8-sigma, guarded
#define HCAP   2560         // per-half sorted capacity; mean 2048, ~11-sigma, guarded
#define CHUNK3 3200         // edges per bplace block (256 thr): grid = 1000

// convert one 16B (8-half) chunk into 8 fp32 accumulators
__device__ __forceinline__ void acc_f4(float (&acc)[8], float4 vf) {
    union { float4 f; __half2 h[4]; } uu; uu.f = vf;
    float2 g0 = __half22float2(uu.h[0]);
    float2 g1 = __half22float2(uu.h[1]);
    float2 g2 = __half22float2(uu.h[2]);
    float2 g3 = __half22float2(uu.h[3]);
    acc[0] += g0.x; acc[1] += g0.y;
    acc[2] += g1.x; acc[3] += g1.y;
    acc[4] += g2.x; acc[5] += g2.y;
    acc[6] += g3.x; acc[7] += g3.y;
}

// ---- zero bcur (graph-capture-safe, ordered before fusedA on the stream) --------
__global__ __launch_bounds__(256) void zero_kernel(int* __restrict__ bcur) {
    ((int4*)bcur)[threadIdx.x] = make_int4(0, 0, 0, 0);   // 256*16B = NBK ints
}

// ---- fused A: gemm1 blocks (32 nodes each) interleaved with bplace blocks -------
// every 4th block (bid&3==3, bq<bpGrid) is a bplace chunk
__global__ __launch_bounds__(256) void fusedA_kernel(const float* __restrict__ feat,
                                                     const float* __restrict__ W1,
                                                     __half* __restrict__ h1,
                                                     const int* __restrict__ src,
                                                     const int* __restrict__ dst,
                                                     int* __restrict__ bcur,
                                                     int* __restrict__ pairs,
                                                     int nNodes, int nEdges, int bpGrid) {
    union Smem {
        struct { float sF[32 * 132]; float sW[N_IN * HID]; } g;                  // 33280 B
        struct { int lh[NBK]; int lcur[NBK]; int gofs[NBK]; int sWS[8];
                 int lst[CHUNK3]; unsigned short lbk[CHUNK3]; } b;               // 31520 B
    };
    __shared__ Smem sm;
    const int tid = threadIdx.x;
    const int bid = blockIdx.x;
    const int bq  = bid >> 2;

    if ((bid & 3) == 3 && bq < bpGrid) {
        // ---------------- bplace: block-staged counting sort into coarse buckets
        int* lh   = sm.b.lh;
        int* lcur = sm.b.lcur;
        int* gofs = sm.b.gofs;
        int* sWS  = sm.b.sWS;
        int* lst  = sm.b.lst;
        unsigned short* lbk = sm.b.lbk;

        const int base = bq * CHUNK3;
        const int m    = min(CHUNK3, nEdges - base);

        ((int4*)lh)[tid] = make_int4(0, 0, 0, 0);   // 256*16B = NBK ints
        __syncthreads();

        int4 dv[3], sv[3];
        bool ok[3];
        #pragma unroll
        for (int k = 0; k < 3; ++k) {
            int e = base + k * 1024 + tid * 4;
            ok[k] = (e < nEdges);          // nEdges % 4 == 0
            if (ok[k]) {
                dv[k] = *(const int4*)(dst + e);
                sv[k] = *(const int4*)(src + e);
            }
        }
        int  dt = 0, st = 0;
        bool okt = (tid < 128) && (base + 3072 + tid < nEdges);
        if (okt) { dt = dst[base + 3072 + tid]; st = src[base + 3072 + tid]; }

        #pragma unroll
        for (int k = 0; k < 3; ++k) {
            if (ok[k]) {
                atomicAdd(&lh[dv[k].x >> RSH], 1);
                atomicAdd(&lh[dv[k].y >> RSH], 1);
                atomicAdd(&lh[dv[k].z >> RSH], 1);
                atomicAdd(&lh[dv[k].w >> RSH], 1);
            }
        }
        if (okt) atomicAdd(&lh[dt >> RSH], 1);
        __syncthreads();

        // scan over NBK counters: 4 per thread, wave shfl scan + 4-wave combine
        int4 c = ((int4*)lh)[tid];
        int tsum = c.x + c.y + c.z + c.w;
        const int lane = tid & 63, wid = tid >> 6;
        int inc = tsum;
        #pragma unroll
        for (int off = 1; off < 64; off <<= 1) {
            int t = __shfl_up(inc, off, 64);
            if (lane >= off) inc += t;
        }
        if (lane == 63) sWS[wid] = inc;
        __syncthreads();
        if (tid == 0) {
            int r = 0;
            #pragma unroll
            for (int w = 0; w < 4; ++w) { int s = sWS[w]; sWS[4 + w] = r; r += s; }
        }
        __syncthreads();
        int excl = sWS[4 + wid] + inc - tsum;
        const int b0 = 4 * tid;
        int e0 = excl, e1 = e0 + c.x, e2 = e1 + c.y, e3 = e2 + c.z;
        lh[b0]   = e0; lh[b0+1]   = e1; lh[b0+2]   = e2; lh[b0+3]   = e3;
        lcur[b0] = e0; lcur[b0+1] = e1; lcur[b0+2] = e2; lcur[b0+3] = e3;
        gofs[b0]   = (c.x > 0) ? atomicAdd(&bcur[b0],   c.x) : 0;
        gofs[b0+1] = (c.y > 0) ? atomicAdd(&bcur[b0+1], c.y) : 0;
        gofs[b0+2] = (c.z > 0) ? atomicAdd(&bcur[b0+2], c.z) : 0;
        gofs[b0+3] = (c.w > 0) ? atomicAdd(&bcur[b0+3], c.w) : 0;
        __syncthreads();

        #pragma unroll
        for (int k = 0; k < 3; ++k) {
            if (ok[k]) {
                int b, p;
                b = dv[k].x >> RSH; p = atomicAdd(&lcur[b], 1); lst[p] = ((dv[k].x & (RNODES-1)) << 17) | sv[k].x; lbk[p] = (unsigned short)b;
                b = dv[k].y >> RSH; p = atomicAdd(&lcur[b], 1); lst[p] = ((dv[k].y & (RNODES-1)) << 17) | sv[k].y; lbk[p] = (unsigned short)b;
                b = dv[k].z >> RSH; p = atomicAdd(&lcur[b], 1); lst[p] = ((dv[k].z & (RNODES-1)) << 17) | sv[k].z; lbk[p] = (unsigned short)b;
                b = dv[k].w >> RSH; p = atomicAdd(&lcur[b], 1); lst[p] = ((dv[k].w & (RNODES-1)) << 17) | sv[k].w; lbk[p] = (unsigned short)b;
            }
        }
        if (okt) {
            int b = dt >> RSH, p = atomicAdd(&lcur[b], 1);
            lst[p] = ((dt & (RNODES-1)) << 17) | st; lbk[p] = (unsigned short)b;
        }
        __syncthreads();

        for (int i = tid; i < m; i += 256) {
            int b = lbk[i];
            int rank = gofs[b] + (i - lh[b]);
            if (rank < BCAP) pairs[(size_t)b * BCAP + rank] = lst[i];
        }
    } else {
        // ---------------- gemm1: 32 nodes, 8 threads/node
        const int gb = bid - min((bid + 1) >> 2, bpGrid);
        const int nb = gb * 32;

        {
            const float4* Wv  = (const float4*)W1;
            float4*       sWv = (float4*)sm.g.sW;
            #pragma unroll
            for (int i = 0; i < 4; ++i) sWv[tid + 256 * i] = Wv[tid + 256 * i];
        }
        #pragma unroll
        for (int i = 0; i < 4; ++i) {
            int f   = tid + 256 * i;
            int row = f >> 5;
            int c4  = f & 31;
            int n   = nb + row;
            float4 v = make_float4(0.f, 0.f, 0.f, 0.f);
            if (n < nNodes) v = *(const float4*)(feat + (size_t)n * N_IN + c4 * 4);
            *(float4*)(sm.g.sF + row * 132 + c4 * 4) = v;
        }
        __syncthreads();

        const int og = tid & 7;
        const int ng = tid >> 3;
        const int o0 = og * 4;
        const float* f0 = sm.g.sF + ng * 132;

        float acc0[4] = {0.f, 0.f, 0.f, 0.f};
        #pragma unroll 8
        for (int k = 0; k < N_IN; k += 4) {
            float4 a0 = *(const float4*)(f0 + k);
            const float a0v[4] = {a0.x, a0.y, a0.z, a0.w};
            #pragma unroll
            for (int j = 0; j < 4; ++j) {
                float4 w = *(const float4*)(sm.g.sW + (k + j) * HID + o0);
                acc0[0] += a0v[j] * w.x; acc0[1] += a0v[j] * w.y;
                acc0[2] += a0v[j] * w.z; acc0[3] += a0v[j] * w.w;
            }
        }
        int n0 = nb + ng;
        if (n0 < nNodes) {
            union { __half2 h[2]; float2 f; } u;
            u.h[0] = __floats2half2_rn(acc0[0], acc0[1]);
            u.h[1] = __floats2half2_rn(acc0[2], acc0[3]);
            *(float2*)(h1 + (size_t)n0 * HID + o0) = u.f;
        }
    }
}

// ---- L1: per half-bucket (64 nodes) sort in LDS + gather h1 + fin1 + gemm2 ------
__global__ __launch_bounds__(512) void l1_kernel(const __half* __restrict__ h1,
                                                 const int* __restrict__ bcur,
                                                 const int* __restrict__ pairs,
                                                 const float* __restrict__ b1,
                                                 const float* __restrict__ W2,
                                                 __half* __restrict__ h2, int nNodes) {
    __shared__ int   sorted[HCAP];
    __shared__ int   hist[64];
    __shared__ int   scn[64];
    __shared__ int   cur[64];
    __shared__ float sW2[HID * ODIM];
    const int tid = threadIdx.x;
    const int bkt = blockIdx.x >> 1;
    const int h   = blockIdx.x & 1;
    const int cnt = min(bcur[bkt], BCAP);
    const size_t pb = (size_t)bkt * BCAP;

    if (tid < 64) hist[tid] = 0;
    if (tid < 96) ((float4*)sW2)[tid] = ((const float4*)W2)[tid];
    __syncthreads();

    int vreg[9];
    #pragma unroll
    for (int u = 0; u < 9; ++u) {
        int i = tid + u * 512;
        if (i < cnt) {
            int v = pairs[pb + i];
            vreg[u] = v;
            if (((v >> 17) >> 6) == h) atomicAdd(&hist[(v >> 17) & 63], 1);
        }
    }
    __syncthreads();

    if (tid < 64) {
        int v0 = hist[tid], inc = v0;
        #pragma unroll
        for (int off = 1; off < 64; off <<= 1) {
            int t = __shfl_up(inc, off, 64);
            if (tid >= off) inc += t;
        }
        scn[tid] = inc - v0;
        cur[tid] = inc - v0;
    }
    __syncthreads();

    #pragma unroll
    for (int u = 0; u < 9; ++u) {
        int i = tid + u * 512;
        if (i < cnt) {
            int v = vreg[u];
            if (((v >> 17) >> 6) == h) {
                int pos = atomicAdd(&cur[(v >> 17) & 63], 1);
                if (pos < HCAP) sorted[pos] = v & 0x1FFFF;
            }
        }
    }
    __syncthreads();

    // gather: 8 lanes/node, lane r: quarter q=r&3 of 64B h1 row, edge slot sub=r>>2
    const int r   = tid & 7;
    const int grp = tid >> 3;           // node-in-half 0..63
    const int q   = r & 3;
    const int sub = r >> 2;
    const int n   = bkt * RNODES + h * 64 + grp;
    if (n >= nNodes) return;

    const float4* h1q = (const float4*)h1;
    const int dcnt = hist[grp];
    const int beg  = scn[grp];
    const int end  = beg + dcnt;

    float acc[8] = {0.f, 0.f, 0.f, 0.f, 0.f, 0.f, 0.f, 0.f};
    int i = beg;
    for (; i + 16 <= end; i += 16) {
        float4 v[8];
        #pragma unroll
        for (int u = 0; u < 8; ++u) {
            int e = sorted[i + 2 * u + sub];
            v[u] = h1q[(size_t)e * 4 + q];
        }
        #pragma unroll
        for (int u = 0; u < 8; ++u) acc_f4(acc, v[u]);
    }
    for (; i + 2 <= end; i += 2) {
        int e = sorted[i + sub];
        acc_f4(acc, h1q[(size_t)e * 4 + q]);
    }
    if (i < end && sub == 0) {
        int e = sorted[i];
        acc_f4(acc, h1q[(size_t)e * 4 + q]);
    }

    // combine the two edge slots: lanes r and r^4 hold same quarter
    #pragma unroll
    for (int t = 0; t < 8; ++t) acc[t] += __shfl_xor(acc[t], 4, 8);

    const float rd = 1.f / (float)(dcnt < 1 ? 1 : dcnt);
    float x[8];
    #pragma unroll
    for (int t = 0; t < 8; ++t) {
        float xv = acc[t] * rd + b1[8 * q + t];
        x[t] = xv > 0.f ? xv : 0.f;
    }

    // gemm2: lane r computes out col r (and r+8 if r<4); lanes 0..3 hold quarters 0..3
    const int j0  = r;
    const int j1m = (r < 4) ? (r + 8) : r;
    float o0 = 0.f, o1 = 0.f;
    #pragma unroll
    for (int qq = 0; qq < 4; ++qq) {
        #pragma unroll
        for (int t = 0; t < 8; ++t) {
            float xv = __shfl(x[t], qq, 8);
            int k = 8 * qq + t;
            o0 += xv * sW2[k * ODIM + j0];
            o1 += xv * sW2[k * ODIM + j1m];
        }
    }
    h2[(size_t)n * H2P + j0] = __float2half(o0);
    if (r < 4) h2[(size_t)n * H2P + 8 + r] = __float2half(o1);
}

// ---- L2: per half-bucket (64 nodes) sort in LDS + gather h2 (32 B rows) + fin2 --
__global__ __launch_bounds__(512) void l2_kernel(const __half* __restrict__ h2,
                                                 const int* __restrict__ bcur,
                                                 const int* __restrict__ pairs,
                                                 const float* __restrict__ b2,
                                                 float* __restrict__ out, int nNodes) {
    __shared__ int sorted[HCAP];
    __shared__ int hist[64];
    __shared__ int scn[64];
    __shared__ int cur[64];
    const int tid = threadIdx.x;
    const int bkt = blockIdx.x >> 1;
    const int h   = blockIdx.x & 1;
    const int cnt = min(bcur[bkt], BCAP);
    const size_t pb = (size_t)bkt * BCAP;

    if (tid < 64) hist[tid] = 0;
    __syncthreads();

    int vreg[9];
    #pragma unroll
    for (int u = 0; u < 9; ++u) {
        int i = tid + u * 512;
        if (i < cnt) {
            int v = pairs[pb + i];
            vreg[u] = v;
            if (((v >> 17) >> 6) == h) atomicAdd(&hist[(v >> 17) & 63], 1);
        }
    }
    __syncthreads();

    if (tid < 64) {
        int v0 = hist[tid], inc = v0;
        #pragma unroll
        for (int off = 1; off < 64; off <<= 1) {
            int t = __shfl_up(inc, off, 64);
            if (tid >= off) inc += t;
        }
        scn[tid] = inc - v0;
        cur[tid] = inc - v0;
    }
    __syncthreads();

    #pragma unroll
    for (int u = 0; u < 9; ++u) {
        int i = tid + u * 512;
        if (i < cnt) {
            int v = vreg[u];
            if (((v >> 17) >> 6) == h) {
                int pos = atomicAdd(&cur[(v >> 17) & 63], 1);
                if (pos < HCAP) sorted[pos] = v & 0x1FFFF;
            }
        }
    }
    __syncthreads();

    // gather: 8 lanes/node, lane r: half=r&1 of 32B h2 row, edge slot sub=r>>1 (0..3)
    const int r    = tid & 7;
    const int grp  = tid >> 3;
    const int half = r & 1;
    const int sub  = r >> 1;
    const int n    = bkt * RNODES + h * 64 + grp;
    if (n >= nNodes) return;

    const float4* h2q = (const float4*)h2;   // row e at index e*2 (32B padded)
    const int dcnt = hist[grp];
    const int beg  = scn[grp];
    const int end  = beg + dcnt;

    float acc[8] = {0.f, 0.f, 0.f, 0.f, 0.f, 0.f, 0.f, 0.f};
    int i = beg;
    for (; i + 32 <= end; i += 32) {
        float4 v[8];
        #pragma unroll
        for (int u = 0; u < 8; ++u) {
            int e = sorted[i + 4 * u + sub];
            v[u] = h2q[(size_t)e * 2 + half];
        }
        #pragma unroll
        for (int u = 0; u < 8; ++u) acc_f4(acc, v[u]);
    }
    for (; i + 4 <= end; i += 4) {
        int e = sorted[i + sub];
        acc_f4(acc, h2q[(size_t)e * 2 + half]);
    }
    const int rem = end - i;
    if (sub < rem) {
        int e = sorted[i + sub];
        acc_f4(acc, h2q[(size_t)e * 2 + half]);
    }

    // combine the 4 edge slots: lanes with same (r&1) hold same half-row
    #pragma unroll
    for (int t = 0; t < 8; ++t) {
        acc[t] += __shfl_xor(acc[t], 2, 8);
        acc[t] += __shfl_xor(acc[t], 4, 8);
    }

    const float rd = 1.f / (float)(dcnt < 1 ? 1 : dcnt);
    if (r == 0) {
        float w[8];
        #pragma unroll
        for (int t = 0; t < 8; ++t) {
            float wv = acc[t] * rd + b2[t];
            w[t] = wv > 0.f ? wv : 0.f;
        }
        *(float4*)(out + (size_t)n * ODIM)     = make_float4(w[0], w[1], w[2], w[3]);
        *(float4*)(out + (size_t)n * ODIM + 4) = make_float4(w[4], w[5], w[6], w[7]);
    } else if (r == 1) {
        float w[4];
        #pragma unroll
        for (int t = 0; t < 4; ++t) {
            float wv = acc[t] * rd + b2[8 + t];
            w[t] = wv > 0.f ? wv : 0.f;
        }
        *(float4*)(out + (size_t)n * ODIM + 8) = make_float4(w[0], w[1], w[2], w[3]);
    }
}

extern "C" void kernel_launch(void* const* d_in, const int* in_sizes, int n_in,
                              void* d_out, int out_size, void* d_ws, size_t ws_size,
                              hipStream_t stream) {
    const float* feat = (const float*)d_in[0];
    const int*   src  = (const int*)d_in[1];
    const int*   dst  = (const int*)d_in[2];
    const float* W1   = (const float*)d_in[3];
    const float* b1   = (const float*)d_in[4];
    const float* W2   = (const float*)d_in[5];
    const float* b2   = (const float*)d_in[6];
    float* out = (float*)d_out;

    const int nEdges = in_sizes[1];
    const int nNodes = in_sizes[0] / N_IN;                 // 100000
    const int gpGrid = (nNodes + 31) / 32;                 // 3125 gemm1 blocks
    const int bpGrid = (nEdges + CHUNK3 - 1) / CHUNK3;     // 1000 bplace blocks
    const int hbGrid = (nNodes + 63) / 64;                 // 1563 half-bucket blocks

    // ws: h1[N*32] h | h2[N*16] h | bcur[NBK] i | pairs[NBMAX*BCAP] i
    __half* h1    = (__half*)d_ws;
    __half* h2    = h1 + (size_t)nNodes * HID;
    int*    bcur  = (int*)(h2 + (size_t)nNodes * H2P);
    int*    pairs = bcur + NBK;

    zero_kernel<<<1, 256, 0, stream>>>(bcur);
    fusedA_kernel<<<gpGrid + bpGrid, 256, 0, stream>>>(feat, W1, h1, src, dst, bcur,
                                                       pairs, nNodes, nEdges, bpGrid);
    l1_kernel<<<hbGrid, 512, 0, stream>>>(h1, bcur, pairs, b1, W2, h2, nNodes);
    l2_kernel<<<hbGrid, 512, 0, stream>>>(h2, bcur, pairs, b2, out, nNodes);
}

// Round 8
// 230.240 us; speedup vs baseline: 1.2444x; 1.2444x over previous
//
#include <hip/hip_runtime.h>
#include <hip/hip_fp16.h>

#define N_IN   128
#define HID    32
#define ODIM   12
#define H2P    16           // padded h2 row: 16 halves = 32 B aligned
#define RNODES 128          // nodes per bucket (dst >> 7)
#define RSH    7
#define NBMAX  800          // >= ceil(100000/128) = 782
#define NBK    1024         // bucket counter count (pow2)
#define BCAP   4608         // bucket capacity; mean 4096, ~8-sigma, guarded
#define CHUNK  6400         // edges per bplace block -> grid 500, 3 blk/CU (49.7KB LDS)

// ------ GEMM1: h1[n][32] = feat[n][0:128] @ W1 (fp16 out); block 0 zeroes bcur --
__global__ __launch_bounds__(256) void gemm1_kernel(const float* __restrict__ feat,
                                                    const float* __restrict__ W1,
                                                    __half* __restrict__ h1,
                                                    int* __restrict__ bcur, int nNodes) {
    if (blockIdx.x == 0) {
        ((int4*)bcur)[threadIdx.x] = make_int4(0, 0, 0, 0);   // 256*16B = NBK ints
    }
    __shared__ float sF[64 * 132];
    __shared__ float sW[N_IN * HID];
    const int tid = threadIdx.x;
    const int nb  = blockIdx.x * 64;

    {
        const float4* Wv  = (const float4*)W1;
        float4*       sWv = (float4*)sW;
        #pragma unroll
        for (int i = 0; i < 4; ++i) sWv[tid + 256 * i] = Wv[tid + 256 * i];
    }
    #pragma unroll
    for (int i = 0; i < 8; ++i) {
        int f   = tid + 256 * i;
        int row = f >> 5;
        int c4  = f & 31;
        int n   = nb + row;
        float4 v = make_float4(0.f, 0.f, 0.f, 0.f);
        if (n < nNodes) v = *(const float4*)(feat + (size_t)n * N_IN + c4 * 4);
        *(float4*)(sF + row * 132 + c4 * 4) = v;
    }
    __syncthreads();

    const int og = tid & 7;
    const int ng = tid >> 3;
    const int o0 = og * 4;
    const float* f0 = sF + ng * 132;
    const float* f1 = sF + (ng + 32) * 132;

    float acc0[4] = {0.f, 0.f, 0.f, 0.f};
    float acc1[4] = {0.f, 0.f, 0.f, 0.f};
    #pragma unroll 8
    for (int k = 0; k < N_IN; k += 4) {
        float4 a0 = *(const float4*)(f0 + k);
        float4 a1 = *(const float4*)(f1 + k);
        const float a0v[4] = {a0.x, a0.y, a0.z, a0.w};
        const float a1v[4] = {a1.x, a1.y, a1.z, a1.w};
        #pragma unroll
        for (int j = 0; j < 4; ++j) {
            float4 w = *(const float4*)(sW + (k + j) * HID + o0);
            acc0[0] += a0v[j] * w.x; acc0[1] += a0v[j] * w.y;
            acc0[2] += a0v[j] * w.z; acc0[3] += a0v[j] * w.w;
            acc1[0] += a1v[j] * w.x; acc1[1] += a1v[j] * w.y;
            acc1[2] += a1v[j] * w.z; acc1[3] += a1v[j] * w.w;
        }
    }
    int n0 = nb + ng, n1 = nb + ng + 32;
    if (n0 < nNodes) {
        union { __half2 h[2]; float2 f; } u;
        u.h[0] = __floats2half2_rn(acc0[0], acc0[1]);
        u.h[1] = __floats2half2_rn(acc0[2], acc0[3]);
        *(float2*)(h1 + (size_t)n0 * HID + o0) = u.f;
    }
    if (n1 < nNodes) {
        union { __half2 h[2]; float2 f; } u;
        u.h[0] = __floats2half2_rn(acc1[0], acc1[1]);
        u.h[1] = __floats2half2_rn(acc1[2], acc1[3]);
        *(float2*)(h1 + (size_t)n1 * HID + o0) = u.f;
    }
}

// ------- bplace: block-staged counting sort by bucket, coalesced run writes ------
__global__ __launch_bounds__(512) void bplace_kernel(const int* __restrict__ src,
                                                     const int* __restrict__ dst,
                                                     int* __restrict__ bcur,
                                                     int* __restrict__ pairs, int nEdges) {
    __shared__ int      lh[NBK];
    __shared__ int      lcur[NBK];
    __shared__ int      gofs[NBK];
    __shared__ int      sWS[16];
    __shared__ int      lst[CHUNK];
    __shared__ unsigned short lbk[CHUNK];

    const int tid  = threadIdx.x;
    const int base = blockIdx.x * CHUNK;
    const int m    = min(CHUNK, nEdges - base);

    ((int2*)lh)[tid] = make_int2(0, 0);   // 512*8B = NBK ints
    __syncthreads();

    // 12 edges via 3 int4 + 1 tail edge for tid<256 (CHUNK = 512*12 + 256)
    int4 dv[3], sv[3];
    bool ok[3];
    #pragma unroll
    for (int k = 0; k < 3; ++k) {
        int e = base + k * 2048 + tid * 4;
        ok[k] = (e < nEdges);          // nEdges % 4 == 0
        if (ok[k]) {
            dv[k] = *(const int4*)(dst + e);
            sv[k] = *(const int4*)(src + e);
        }
    }
    int  dt = 0, st = 0;
    bool okt = (tid < 256) && (base + 6144 + tid < nEdges);
    if (okt) {
        dt = dst[base + 6144 + tid];
        st = src[base + 6144 + tid];
    }
    #pragma unroll
    for (int k = 0; k < 3; ++k) {
        if (ok[k]) {
            atomicAdd(&lh[dv[k].x >> RSH], 1);
            atomicAdd(&lh[dv[k].y >> RSH], 1);
            atomicAdd(&lh[dv[k].z >> RSH], 1);
            atomicAdd(&lh[dv[k].w >> RSH], 1);
        }
    }
    if (okt) atomicAdd(&lh[dt >> RSH], 1);
    __syncthreads();

    // scan over NBK counters: 2 per thread, wave shfl scan + 8-wave combine
    int c0 = lh[2 * tid], c1 = lh[2 * tid + 1];
    int tsum = c0 + c1;
    const int lane = tid & 63, wid = tid >> 6;
    int inc = tsum;
    #pragma unroll
    for (int off = 1; off < 64; off <<= 1) {
        int t = __shfl_up(inc, off, 64);
        if (lane >= off) inc += t;
    }
    if (lane == 63) sWS[wid] = inc;
    __syncthreads();
    if (tid == 0) {
        int r = 0;
        #pragma unroll
        for (int w = 0; w < 8; ++w) { int s = sWS[w]; sWS[8 + w] = r; r += s; }
    }
    __syncthreads();
    int excl = sWS[8 + wid] + inc - tsum;
    lh[2 * tid]       = excl;
    lh[2 * tid + 1]   = excl + c0;
    lcur[2 * tid]     = excl;
    lcur[2 * tid + 1] = excl + c0;
    gofs[2 * tid]     = (c0 > 0) ? atomicAdd(&bcur[2 * tid], c0) : 0;
    gofs[2 * tid + 1] = (c1 > 0) ? atomicAdd(&bcur[2 * tid + 1], c1) : 0;
    __syncthreads();

    #pragma unroll
    for (int k = 0; k < 3; ++k) {
        if (ok[k]) {
            int b, p;
            b = dv[k].x >> RSH; p = atomicAdd(&lcur[b], 1); lst[p] = ((dv[k].x & (RNODES - 1)) << 17) | sv[k].x; lbk[p] = (unsigned short)b;
            b = dv[k].y >> RSH; p = atomicAdd(&lcur[b], 1); lst[p] = ((dv[k].y & (RNODES - 1)) << 17) | sv[k].y; lbk[p] = (unsigned short)b;
            b = dv[k].z >> RSH; p = atomicAdd(&lcur[b], 1); lst[p] = ((dv[k].z & (RNODES - 1)) << 17) | sv[k].z; lbk[p] = (unsigned short)b;
            b = dv[k].w >> RSH; p = atomicAdd(&lcur[b], 1); lst[p] = ((dv[k].w & (RNODES - 1)) << 17) | sv[k].w; lbk[p] = (unsigned short)b;
        }
    }
    if (okt) {
        int b = dt >> RSH, p = atomicAdd(&lcur[b], 1);
        lst[p] = ((dt & (RNODES - 1)) << 17) | st; lbk[p] = (unsigned short)b;
    }
    __syncthreads();

    for (int i = tid; i < m; i += 512) {
        int b = lbk[i];
        int rank = gofs[b] + (i - lh[b]);
        if (rank < BCAP) pairs[(size_t)b * BCAP + rank] = lst[i];
    }
}

// ------- agg1 + fin1 + gemm2; sorts bucket in LDS, exports CSR for agg2 ----------
__global__ __launch_bounds__(512) void agg1_kernel(const __half* __restrict__ h1,
                                                   const int* __restrict__ bcur,
                                                   int* __restrict__ pairs,
                                                   const float* __restrict__ b1,
                                                   const float* __restrict__ W2,
                                                   __half* __restrict__ h2,
                                                   int* __restrict__ rowstartg,
                                                   int* __restrict__ countg, int nNodes) {
    __shared__ int   sorted[BCAP];
    __shared__ int   hist[RNODES];
    __shared__ int   scn[RNODES];
    __shared__ int   cur[RNODES];
    __shared__ int   sws[2];
    __shared__ float sW2[HID * ODIM];
    const int tid = threadIdx.x;
    const int bkt = blockIdx.x;
    const int cnt = min(bcur[bkt], BCAP);
    const size_t pb = (size_t)bkt * BCAP;

    if (tid < RNODES) hist[tid] = 0;
    if (tid < 96) ((float4*)sW2)[tid] = ((const float4*)W2)[tid];
    __syncthreads();

    for (int i = tid; i < cnt; i += 512) atomicAdd(&hist[pairs[pb + i] >> 17], 1);
    __syncthreads();

    // exclusive scan over 128 node counts: two-wave shfl scan + combine
    int v0 = 0, inc = 0;
    if (tid < RNODES) {
        v0 = hist[tid]; inc = v0;
        #pragma unroll
        for (int off = 1; off < 64; off <<= 1) {
            int t = __shfl_up(inc, off, 64);
            if ((tid & 63) >= off) inc += t;
        }
        if ((tid & 63) == 63) sws[tid >> 6] = inc;
    }
    __syncthreads();
    if (tid < RNODES) {
        int add = (tid >= 64) ? sws[0] : 0;
        scn[tid] = add + inc - v0;
        cur[tid] = add + inc - v0;
    }
    __syncthreads();

    for (int i = tid; i < cnt; i += 512) {
        int v = pairs[pb + i];
        int pos = atomicAdd(&cur[v >> 17], 1);
        sorted[pos] = v & 0x1FFFF;
    }
    __syncthreads();

    // export sorted src list + CSR meta for agg2 (coalesced; overlaps gather below)
    for (int i = tid; i < cnt; i += 512) pairs[pb + i] = sorted[i];
    if (tid < RNODES) {
        int n = bkt * RNODES + tid;
        if (n < nNodes) {
            rowstartg[n] = (int)pb + scn[tid];
            countg[n]    = hist[tid];
        }
    }

    // gather: 16 lanes/node (half2 cols), 32 nodes concurrent, 4 passes, 16-deep ILP
    const int c   = tid & 15;
    const int grp = tid >> 4;
    const __half2* h1v = (const __half2*)h1;
    const int col = (c < ODIM) ? c : 0;

    #pragma unroll
    for (int g = 0; g < 4; ++g) {
        int nl = g * 32 + grp;
        int n  = bkt * RNODES + nl;
        if (n >= nNodes) continue;
        int dcnt = hist[nl];
        int beg  = scn[nl];
        int end  = beg + dcnt;

        float2 s0 = {0.f, 0.f}, s1 = {0.f, 0.f}, s2 = {0.f, 0.f}, s3 = {0.f, 0.f};
        int i = beg;
        for (; i + 16 <= end; i += 16) {
            int e0 = sorted[i],      e1 = sorted[i + 1],  e2 = sorted[i + 2],  e3 = sorted[i + 3];
            int e4 = sorted[i + 4],  e5 = sorted[i + 5],  e6 = sorted[i + 6],  e7 = sorted[i + 7];
            int e8 = sorted[i + 8],  e9 = sorted[i + 9],  eA = sorted[i + 10], eB = sorted[i + 11];
            int eC = sorted[i + 12], eD = sorted[i + 13], eE = sorted[i + 14], eF = sorted[i + 15];
            float2 f0 = __half22float2(h1v[(size_t)e0 * 16 + c]);
            float2 f1 = __half22float2(h1v[(size_t)e1 * 16 + c]);
            float2 f2 = __half22float2(h1v[(size_t)e2 * 16 + c]);
            float2 f3 = __half22float2(h1v[(size_t)e3 * 16 + c]);
            float2 f4 = __half22float2(h1v[(size_t)e4 * 16 + c]);
            float2 f5 = __half22float2(h1v[(size_t)e5 * 16 + c]);
            float2 f6 = __half22float2(h1v[(size_t)e6 * 16 + c]);
            float2 f7 = __half22float2(h1v[(size_t)e7 * 16 + c]);
            float2 f8 = __half22float2(h1v[(size_t)e8 * 16 + c]);
            float2 f9 = __half22float2(h1v[(size_t)e9 * 16 + c]);
            float2 fA = __half22float2(h1v[(size_t)eA * 16 + c]);
            float2 fB = __half22float2(h1v[(size_t)eB * 16 + c]);
            float2 fC = __half22float2(h1v[(size_t)eC * 16 + c]);
            float2 fD = __half22float2(h1v[(size_t)eD * 16 + c]);
            float2 fE = __half22float2(h1v[(size_t)eE * 16 + c]);
            float2 fF = __half22float2(h1v[(size_t)eF * 16 + c]);
            s0.x += f0.x; s0.y += f0.y;  s1.x += f1.x; s1.y += f1.y;
            s2.x += f2.x; s2.y += f2.y;  s3.x += f3.x; s3.y += f3.y;
            s0.x += f4.x; s0.y += f4.y;  s1.x += f5.x; s1.y += f5.y;
            s2.x += f6.x; s2.y += f6.y;  s3.x += f7.x; s3.y += f7.y;
            s0.x += f8.x; s0.y += f8.y;  s1.x += f9.x; s1.y += f9.y;
            s2.x += fA.x; s2.y += fA.y;  s3.x += fB.x; s3.y += fB.y;
            s0.x += fC.x; s0.y += fC.y;  s1.x += fD.x; s1.y += fD.y;
            s2.x += fE.x; s2.y += fE.y;  s3.x += fF.x; s3.y += fF.y;
        }
        for (; i + 4 <= end; i += 4) {
            int e0 = sorted[i], e1 = sorted[i + 1], e2 = sorted[i + 2], e3 = sorted[i + 3];
            float2 f0 = __half22float2(h1v[(size_t)e0 * 16 + c]);
            float2 f1 = __half22float2(h1v[(size_t)e1 * 16 + c]);
            float2 f2 = __half22float2(h1v[(size_t)e2 * 16 + c]);
            float2 f3 = __half22float2(h1v[(size_t)e3 * 16 + c]);
            s0.x += f0.x; s0.y += f0.y;  s1.x += f1.x; s1.y += f1.y;
            s2.x += f2.x; s2.y += f2.y;  s3.x += f3.x; s3.y += f3.y;
        }
        for (; i < end; ++i) {
            float2 f = __half22float2(h1v[(size_t)sorted[i] * 16 + c]);
            s0.x += f.x; s0.y += f.y;
        }
        float sumx = (s0.x + s1.x) + (s2.x + s3.x);
        float sumy = (s0.y + s1.y) + (s2.y + s3.y);

        float rd = 1.f / (float)(dcnt < 1 ? 1 : dcnt);
        float x0 = sumx * rd + b1[2 * c];
        float x1 = sumy * rd + b1[2 * c + 1];
        x0 = x0 > 0.f ? x0 : 0.f;
        x1 = x1 > 0.f ? x1 : 0.f;

        float acc = 0.f;
        #pragma unroll
        for (int k = 0; k < 16; ++k) {
            float xk0 = __shfl(x0, k, 16);
            float xk1 = __shfl(x1, k, 16);
            acc += xk0 * sW2[(2 * k) * ODIM + col] + xk1 * sW2[(2 * k + 1) * ODIM + col];
        }
        if (c < ODIM) h2[(size_t)n * H2P + c] = __float2half(acc);   // padded 32 B rows
    }
}

// ------- agg2 + fin2: pure per-node gather on pre-sorted CSR (32 B h2 rows) ------
__global__ __launch_bounds__(256) void agg2_kernel(const __half* __restrict__ h2,
                                                   const int* __restrict__ rowstartg,
                                                   const int* __restrict__ countg,
                                                   const int* __restrict__ eidx,
                                                   const float* __restrict__ b2,
                                                   float* __restrict__ out, int nNodes) {
    const int tid = threadIdx.x;
    const int n = blockIdx.x * 32 + (tid >> 3);
    const int c = tid & 7;
    if (n >= nNodes) return;

    const int cnt = countg[n];
    const int beg = rowstartg[n];
    const int end = beg + cnt;
    const int cc  = (c < 6) ? c : 0;
    const __half2* h2v = (const __half2*)h2;   // row e at index e*8 (padded)

    float2 s0 = {0.f, 0.f}, s1 = {0.f, 0.f}, s2 = {0.f, 0.f}, s3 = {0.f, 0.f};
    int i = beg;
    for (; i + 8 <= end; i += 8) {
        int e0 = eidx[i],     e1 = eidx[i + 1], e2 = eidx[i + 2], e3 = eidx[i + 3];
        int e4 = eidx[i + 4], e5 = eidx[i + 5], e6 = eidx[i + 6], e7 = eidx[i + 7];
        float2 f0 = __half22float2(h2v[(size_t)e0 * 8 + cc]);
        float2 f1 = __half22float2(h2v[(size_t)e1 * 8 + cc]);
        float2 f2 = __half22float2(h2v[(size_t)e2 * 8 + cc]);
        float2 f3 = __half22float2(h2v[(size_t)e3 * 8 + cc]);
        float2 f4 = __half22float2(h2v[(size_t)e4 * 8 + cc]);
        float2 f5 = __half22float2(h2v[(size_t)e5 * 8 + cc]);
        float2 f6 = __half22float2(h2v[(size_t)e6 * 8 + cc]);
        float2 f7 = __half22float2(h2v[(size_t)e7 * 8 + cc]);
        s0.x += f0.x; s0.y += f0.y;  s1.x += f1.x; s1.y += f1.y;
        s2.x += f2.x; s2.y += f2.y;  s3.x += f3.x; s3.y += f3.y;
        s0.x += f4.x; s0.y += f4.y;  s1.x += f5.x; s1.y += f5.y;
        s2.x += f6.x; s2.y += f6.y;  s3.x += f7.x; s3.y += f7.y;
    }
    for (; i + 4 <= end; i += 4) {
        int e0 = eidx[i], e1 = eidx[i + 1], e2 = eidx[i + 2], e3 = eidx[i + 3];
        float2 f0 = __half22float2(h2v[(size_t)e0 * 8 + cc]);
        float2 f1 = __half22float2(h2v[(size_t)e1 * 8 + cc]);
        float2 f2 = __half22float2(h2v[(size_t)e2 * 8 + cc]);
        float2 f3 = __half22float2(h2v[(size_t)e3 * 8 + cc]);
        s0.x += f0.x; s0.y += f0.y;  s1.x += f1.x; s1.y += f1.y;
        s2.x += f2.x; s2.y += f2.y;  s3.x += f3.x; s3.y += f3.y;
    }
    for (; i < end; ++i) {
        float2 f = __half22float2(h2v[(size_t)eidx[i] * 8 + cc]);
        s0.x += f.x; s0.y += f.y;
    }
    float sumx = (s0.x + s1.x) + (s2.x + s3.x);
    float sumy = (s0.y + s1.y) + (s2.y + s3.y);

    float rd = 1.f / (float)(cnt < 1 ? 1 : cnt);
    float w0 = sumx * rd + b2[2 * cc];
    float w1 = sumy * rd + b2[2 * cc + 1];
    w0 = w0 > 0.f ? w0 : 0.f;
    w1 = w1 > 0.f ? w1 : 0.f;
    if (c < 6) *(float2*)(out + (size_t)n * ODIM + 2 * c) = make_float2(w0, w1);
}

extern "C" void kernel_launch(void* const* d_in, const int* in_sizes, int n_in,
                              void* d_out, int out_size, void* d_ws, size_t ws_size,
                              hipStream_t stream) {
    const float* feat = (const float*)d_in[0];
    const int*   src  = (const int*)d_in[1];
    const int*   dst  = (const int*)d_in[2];
    const float* W1   = (const float*)d_in[3];
    const float* b1   = (const float*)d_in[4];
    const float* W2   = (const float*)d_in[5];
    const float* b2   = (const float*)d_in[6];
    float* out = (float*)d_out;

    const int nEdges = in_sizes[1];
    const int nNodes = in_sizes[0] / N_IN;   // 100000
    const int nb     = (nNodes + RNODES - 1) / RNODES;   // 782

    // ws: h1[N*32] h | h2[N*16] h | rowstart[N] i | countg[N] i | bcur[NBK] i |
    //     pairs[NBMAX*BCAP] i
    __half* h1       = (__half*)d_ws;
    __half* h2       = h1 + (size_t)nNodes * HID;
    int*    rowstart = (int*)(h2 + (size_t)nNodes * H2P);
    int*    countg   = rowstart + nNodes;
    int*    bcur     = countg + nNodes;
    int*    pairs    = bcur + NBK;

    gemm1_kernel<<<(nNodes + 63) / 64, 256, 0, stream>>>(feat, W1, h1, bcur, nNodes);
    bplace_kernel<<<(nEdges + CHUNK - 1) / CHUNK, 512, 0, stream>>>(src, dst, bcur, pairs, nEdges);
    agg1_kernel<<<nb, 512, 0, stream>>>(h1, bcur, pairs, b1, W2, h2, rowstart, countg, nNodes);
    agg2_kernel<<<(nNodes + 31) / 32, 256, 0, stream>>>(h2, rowstart, countg, pairs, b2, out, nNodes);
}

// Round 9
// 225.470 us; speedup vs baseline: 1.2707x; 1.0212x over previous
//
#include <hip/hip_runtime.h>
#include <hip/hip_fp16.h>

#define N_IN   128
#define HID    32
#define ODIM   12
#define H2P    16           // padded h2 row: 16 halves = 32 B aligned
#define RNODES 128          // nodes per coarse bucket (dst >> 7)
#define RSH    7
#define NBMAX  800          // >= ceil(100000/128) = 782
#define NBK    1024         // bucket counter count (pow2)
#define BCAP   4608         // bucket capacity; mean 4096, ~8-sigma, guarded (9*512)
#define HCAP   2560         // per-half sorted capacity; mean 2048, ~11-sigma, guarded
#define CHUNK  8192         // edges per bplace block (R0 proven config)

// convert one 16B (8-half) chunk into 8 fp32 accumulators
__device__ __forceinline__ void acc_f4(float (&acc)[8], float4 vf) {
    union { float4 f; __half2 h[4]; } uu; uu.f = vf;
    float2 g0 = __half22float2(uu.h[0]);
    float2 g1 = __half22float2(uu.h[1]);
    float2 g2 = __half22float2(uu.h[2]);
    float2 g3 = __half22float2(uu.h[3]);
    acc[0] += g0.x; acc[1] += g0.y;
    acc[2] += g1.x; acc[3] += g1.y;
    acc[4] += g2.x; acc[5] += g2.y;
    acc[6] += g3.x; acc[7] += g3.y;
}

// ------ GEMM1: h1[n][32] = feat[n][0:128] @ W1 (fp16 out); block 0 zeroes bcur --
__global__ __launch_bounds__(256) void gemm1_kernel(const float* __restrict__ feat,
                                                    const float* __restrict__ W1,
                                                    __half* __restrict__ h1,
                                                    int* __restrict__ bcur, int nNodes) {
    if (blockIdx.x == 0) {
        ((int4*)bcur)[threadIdx.x] = make_int4(0, 0, 0, 0);   // 256*16B = NBK ints
    }
    __shared__ float sF[64 * 132];
    __shared__ float sW[N_IN * HID];
    const int tid = threadIdx.x;
    const int nb  = blockIdx.x * 64;

    {
        const float4* Wv  = (const float4*)W1;
        float4*       sWv = (float4*)sW;
        #pragma unroll
        for (int i = 0; i < 4; ++i) sWv[tid + 256 * i] = Wv[tid + 256 * i];
    }
    #pragma unroll
    for (int i = 0; i < 8; ++i) {
        int f   = tid + 256 * i;
        int row = f >> 5;
        int c4  = f & 31;
        int n   = nb + row;
        float4 v = make_float4(0.f, 0.f, 0.f, 0.f);
        if (n < nNodes) v = *(const float4*)(feat + (size_t)n * N_IN + c4 * 4);
        *(float4*)(sF + row * 132 + c4 * 4) = v;
    }
    __syncthreads();

    const int og = tid & 7;
    const int ng = tid >> 3;
    const int o0 = og * 4;
    const float* f0 = sF + ng * 132;
    const float* f1 = sF + (ng + 32) * 132;

    float acc0[4] = {0.f, 0.f, 0.f, 0.f};
    float acc1[4] = {0.f, 0.f, 0.f, 0.f};
    #pragma unroll 8
    for (int k = 0; k < N_IN; k += 4) {
        float4 a0 = *(const float4*)(f0 + k);
        float4 a1 = *(const float4*)(f1 + k);
        const float a0v[4] = {a0.x, a0.y, a0.z, a0.w};
        const float a1v[4] = {a1.x, a1.y, a1.z, a1.w};
        #pragma unroll
        for (int j = 0; j < 4; ++j) {
            float4 w = *(const float4*)(sW + (k + j) * HID + o0);
            acc0[0] += a0v[j] * w.x; acc0[1] += a0v[j] * w.y;
            acc0[2] += a0v[j] * w.z; acc0[3] += a0v[j] * w.w;
            acc1[0] += a1v[j] * w.x; acc1[1] += a1v[j] * w.y;
            acc1[2] += a1v[j] * w.z; acc1[3] += a1v[j] * w.w;
        }
    }
    int n0 = nb + ng, n1 = nb + ng + 32;
    if (n0 < nNodes) {
        union { __half2 h[2]; float2 f; } u;
        u.h[0] = __floats2half2_rn(acc0[0], acc0[1]);
        u.h[1] = __floats2half2_rn(acc0[2], acc0[3]);
        *(float2*)(h1 + (size_t)n0 * HID + o0) = u.f;
    }
    if (n1 < nNodes) {
        union { __half2 h[2]; float2 f; } u;
        u.h[0] = __floats2half2_rn(acc1[0], acc1[1]);
        u.h[1] = __floats2half2_rn(acc1[2], acc1[3]);
        *(float2*)(h1 + (size_t)n1 * HID + o0) = u.f;
    }
}

// ------- bplace: block-staged counting sort by bucket, coalesced run writes ------
__global__ __launch_bounds__(512) void bplace_kernel(const int* __restrict__ src,
                                                     const int* __restrict__ dst,
                                                     int* __restrict__ bcur,
                                                     int* __restrict__ pairs, int nEdges) {
    __shared__ int      lh[NBK];
    __shared__ int      lcur[NBK];
    __shared__ int      gofs[NBK];
    __shared__ int      sWS[16];
    __shared__ int      lst[CHUNK];
    __shared__ unsigned short lbk[CHUNK];

    const int tid  = threadIdx.x;
    const int base = blockIdx.x * CHUNK;
    const int m    = min(CHUNK, nEdges - base);

    ((int2*)lh)[tid] = make_int2(0, 0);   // 512*8B = NBK ints
    __syncthreads();

    int4 dv[4], sv[4];
    bool ok[4];
    #pragma unroll
    for (int k = 0; k < 4; ++k) {
        int e = base + k * 2048 + tid * 4;
        ok[k] = (e < nEdges);          // nEdges % 4 == 0
        if (ok[k]) {
            dv[k] = *(const int4*)(dst + e);
            sv[k] = *(const int4*)(src + e);
        }
    }
    #pragma unroll
    for (int k = 0; k < 4; ++k) {
        if (ok[k]) {
            atomicAdd(&lh[dv[k].x >> RSH], 1);
            atomicAdd(&lh[dv[k].y >> RSH], 1);
            atomicAdd(&lh[dv[k].z >> RSH], 1);
            atomicAdd(&lh[dv[k].w >> RSH], 1);
        }
    }
    __syncthreads();

    // scan over NBK counters: 2 per thread, wave shfl scan + 8-wave combine
    int c0 = lh[2 * tid], c1 = lh[2 * tid + 1];
    int tsum = c0 + c1;
    const int lane = tid & 63, wid = tid >> 6;
    int inc = tsum;
    #pragma unroll
    for (int off = 1; off < 64; off <<= 1) {
        int t = __shfl_up(inc, off, 64);
        if (lane >= off) inc += t;
    }
    if (lane == 63) sWS[wid] = inc;
    __syncthreads();
    if (tid == 0) {
        int r = 0;
        #pragma unroll
        for (int w = 0; w < 8; ++w) { int s = sWS[w]; sWS[8 + w] = r; r += s; }
    }
    __syncthreads();
    int excl = sWS[8 + wid] + inc - tsum;
    lh[2 * tid]       = excl;
    lh[2 * tid + 1]   = excl + c0;
    lcur[2 * tid]     = excl;
    lcur[2 * tid + 1] = excl + c0;
    gofs[2 * tid]     = (c0 > 0) ? atomicAdd(&bcur[2 * tid], c0) : 0;
    gofs[2 * tid + 1] = (c1 > 0) ? atomicAdd(&bcur[2 * tid + 1], c1) : 0;
    __syncthreads();

    #pragma unroll
    for (int k = 0; k < 4; ++k) {
        if (ok[k]) {
            int b, p;
            b = dv[k].x >> RSH; p = atomicAdd(&lcur[b], 1); lst[p] = ((dv[k].x & (RNODES - 1)) << 17) | sv[k].x; lbk[p] = (unsigned short)b;
            b = dv[k].y >> RSH; p = atomicAdd(&lcur[b], 1); lst[p] = ((dv[k].y & (RNODES - 1)) << 17) | sv[k].y; lbk[p] = (unsigned short)b;
            b = dv[k].z >> RSH; p = atomicAdd(&lcur[b], 1); lst[p] = ((dv[k].z & (RNODES - 1)) << 17) | sv[k].z; lbk[p] = (unsigned short)b;
            b = dv[k].w >> RSH; p = atomicAdd(&lcur[b], 1); lst[p] = ((dv[k].w & (RNODES - 1)) << 17) | sv[k].w; lbk[p] = (unsigned short)b;
        }
    }
    __syncthreads();

    for (int i = tid; i < m; i += 512) {
        int b = lbk[i];
        int rank = gofs[b] + (i - lh[b]);
        if (rank < BCAP) pairs[(size_t)b * BCAP + rank] = lst[i];
    }
}

// ---- L1: per half-bucket (64 nodes) sort in LDS + gather h1 + fin1 + gemm2 ------
// gather body = R1's measured-best (16 lanes/node half2, 8-deep, 28 VGPR, 45.4 us)
__global__ __launch_bounds__(512) void l1_kernel(const __half* __restrict__ h1,
                                                 const int* __restrict__ bcur,
                                                 const int* __restrict__ pairs,
                                                 const float* __restrict__ b1,
                                                 const float* __restrict__ W2,
                                                 __half* __restrict__ h2, int nNodes) {
    __shared__ int   sorted[HCAP];
    __shared__ int   hist[64];
    __shared__ int   scn[64];
    __shared__ int   cur[64];
    __shared__ float sW2[HID * ODIM];
    const int tid = threadIdx.x;
    const int bkt = blockIdx.x >> 1;
    const int h   = blockIdx.x & 1;
    const int cnt = min(bcur[bkt], BCAP);
    const size_t pb = (size_t)bkt * BCAP;

    if (tid < 64) hist[tid] = 0;
    if (tid < 96) ((float4*)sW2)[tid] = ((const float4*)W2)[tid];
    __syncthreads();

    int vreg[9];
    #pragma unroll
    for (int u = 0; u < 9; ++u) {
        int i = tid + u * 512;
        if (i < cnt) {
            int v = pairs[pb + i];
            vreg[u] = v;
            if (((v >> 17) >> 6) == h) atomicAdd(&hist[(v >> 17) & 63], 1);
        }
    }
    __syncthreads();

    if (tid < 64) {
        int v0 = hist[tid], inc = v0;
        #pragma unroll
        for (int off = 1; off < 64; off <<= 1) {
            int t = __shfl_up(inc, off, 64);
            if (tid >= off) inc += t;
        }
        scn[tid] = inc - v0;
        cur[tid] = inc - v0;
    }
    __syncthreads();

    #pragma unroll
    for (int u = 0; u < 9; ++u) {
        int i = tid + u * 512;
        if (i < cnt) {
            int v = vreg[u];
            if (((v >> 17) >> 6) == h) {
                int pos = atomicAdd(&cur[(v >> 17) & 63], 1);
                if (pos < HCAP) sorted[pos] = v & 0x1FFFF;
            }
        }
    }
    __syncthreads();

    // gather: 16 lanes/node (half2 cols), 32 nodes concurrent, 2 passes, 8-deep ILP
    const int c   = tid & 15;
    const int grp = tid >> 4;
    const __half2* h1v = (const __half2*)h1;
    const int col = (c < ODIM) ? c : 0;

    #pragma unroll
    for (int g = 0; g < 2; ++g) {
        int nl = g * 32 + grp;
        int n  = bkt * RNODES + h * 64 + nl;
        if (n >= nNodes) continue;
        int dcnt = hist[nl];
        int beg  = scn[nl];
        int end  = beg + dcnt;

        float2 s0 = {0.f, 0.f}, s1 = {0.f, 0.f}, s2 = {0.f, 0.f}, s3 = {0.f, 0.f};
        int i = beg;
        for (; i + 8 <= end; i += 8) {
            int e0 = sorted[i],     e1 = sorted[i + 1], e2 = sorted[i + 2], e3 = sorted[i + 3];
            int e4 = sorted[i + 4], e5 = sorted[i + 5], e6 = sorted[i + 6], e7 = sorted[i + 7];
            float2 f0 = __half22float2(h1v[(size_t)e0 * 16 + c]);
            float2 f1 = __half22float2(h1v[(size_t)e1 * 16 + c]);
            float2 f2 = __half22float2(h1v[(size_t)e2 * 16 + c]);
            float2 f3 = __half22float2(h1v[(size_t)e3 * 16 + c]);
            float2 f4 = __half22float2(h1v[(size_t)e4 * 16 + c]);
            float2 f5 = __half22float2(h1v[(size_t)e5 * 16 + c]);
            float2 f6 = __half22float2(h1v[(size_t)e6 * 16 + c]);
            float2 f7 = __half22float2(h1v[(size_t)e7 * 16 + c]);
            s0.x += f0.x; s0.y += f0.y;  s1.x += f1.x; s1.y += f1.y;
            s2.x += f2.x; s2.y += f2.y;  s3.x += f3.x; s3.y += f3.y;
            s0.x += f4.x; s0.y += f4.y;  s1.x += f5.x; s1.y += f5.y;
            s2.x += f6.x; s2.y += f6.y;  s3.x += f7.x; s3.y += f7.y;
        }
        for (; i + 4 <= end; i += 4) {
            int e0 = sorted[i], e1 = sorted[i + 1], e2 = sorted[i + 2], e3 = sorted[i + 3];
            float2 f0 = __half22float2(h1v[(size_t)e0 * 16 + c]);
            float2 f1 = __half22float2(h1v[(size_t)e1 * 16 + c]);
            float2 f2 = __half22float2(h1v[(size_t)e2 * 16 + c]);
            float2 f3 = __half22float2(h1v[(size_t)e3 * 16 + c]);
            s0.x += f0.x; s0.y += f0.y;  s1.x += f1.x; s1.y += f1.y;
            s2.x += f2.x; s2.y += f2.y;  s3.x += f3.x; s3.y += f3.y;
        }
        for (; i < end; ++i) {
            float2 f = __half22float2(h1v[(size_t)sorted[i] * 16 + c]);
            s0.x += f.x; s0.y += f.y;
        }
        float sumx = (s0.x + s1.x) + (s2.x + s3.x);
        float sumy = (s0.y + s1.y) + (s2.y + s3.y);

        float rd = 1.f / (float)(dcnt < 1 ? 1 : dcnt);
        float x0 = sumx * rd + b1[2 * c];
        float x1 = sumy * rd + b1[2 * c + 1];
        x0 = x0 > 0.f ? x0 : 0.f;
        x1 = x1 > 0.f ? x1 : 0.f;

        float acc = 0.f;
        #pragma unroll
        for (int k = 0; k < 16; ++k) {
            float xk0 = __shfl(x0, k, 16);
            float xk1 = __shfl(x1, k, 16);
            acc += xk0 * sW2[(2 * k) * ODIM + col] + xk1 * sW2[(2 * k + 1) * ODIM + col];
        }
        if (c < ODIM) h2[(size_t)n * H2P + c] = __float2half(acc);   // padded 32 B rows
    }
}

// ---- L2: per half-bucket (64 nodes) sort in LDS + gather h2 (32 B rows) + fin2 --
__global__ __launch_bounds__(512) void l2_kernel(const __half* __restrict__ h2,
                                                 const int* __restrict__ bcur,
                                                 const int* __restrict__ pairs,
                                                 const float* __restrict__ b2,
                                                 float* __restrict__ out, int nNodes) {
    __shared__ int sorted[HCAP];
    __shared__ int hist[64];
    __shared__ int scn[64];
    __shared__ int cur[64];
    const int tid = threadIdx.x;
    const int bkt = blockIdx.x >> 1;
    const int h   = blockIdx.x & 1;
    const int cnt = min(bcur[bkt], BCAP);
    const size_t pb = (size_t)bkt * BCAP;

    if (tid < 64) hist[tid] = 0;
    __syncthreads();

    int vreg[9];
    #pragma unroll
    for (int u = 0; u < 9; ++u) {
        int i = tid + u * 512;
        if (i < cnt) {
            int v = pairs[pb + i];
            vreg[u] = v;
            if (((v >> 17) >> 6) == h) atomicAdd(&hist[(v >> 17) & 63], 1);
        }
    }
    __syncthreads();

    if (tid < 64) {
        int v0 = hist[tid], inc = v0;
        #pragma unroll
        for (int off = 1; off < 64; off <<= 1) {
            int t = __shfl_up(inc, off, 64);
            if (tid >= off) inc += t;
        }
        scn[tid] = inc - v0;
        cur[tid] = inc - v0;
    }
    __syncthreads();

    #pragma unroll
    for (int u = 0; u < 9; ++u) {
        int i = tid + u * 512;
        if (i < cnt) {
            int v = vreg[u];
            if (((v >> 17) >> 6) == h) {
                int pos = atomicAdd(&cur[(v >> 17) & 63], 1);
                if (pos < HCAP) sorted[pos] = v & 0x1FFFF;
            }
        }
    }
    __syncthreads();

    // gather: 8 lanes/node (64 nodes/block): lane r: half=r&1 of 32B row, slot sub=r>>1
    const int r    = tid & 7;
    const int nl   = tid >> 3;
    const int half = r & 1;
    const int sub  = r >> 1;
    const int n    = bkt * RNODES + h * 64 + nl;
    if (n >= nNodes) return;

    const float4* h2q = (const float4*)h2;   // row e at index e*2 (32B padded)
    const int dcnt = hist[nl];
    const int beg  = scn[nl];
    const int end  = beg + dcnt;

    float acc[8] = {0.f, 0.f, 0.f, 0.f, 0.f, 0.f, 0.f, 0.f};
    int i = beg;
    for (; i + 32 <= end; i += 32) {
        float4 v[8];
        #pragma unroll
        for (int u = 0; u < 8; ++u) {
            int e = sorted[i + 4 * u + sub];
            v[u] = h2q[(size_t)e * 2 + half];
        }
        #pragma unroll
        for (int u = 0; u < 8; ++u) acc_f4(acc, v[u]);
    }
    for (; i + 4 <= end; i += 4) {
        int e = sorted[i + sub];
        acc_f4(acc, h2q[(size_t)e * 2 + half]);
    }
    const int rem = end - i;
    if (sub < rem) {
        int e = sorted[i + sub];
        acc_f4(acc, h2q[(size_t)e * 2 + half]);
    }

    // combine the 4 edge slots: lanes with same (r&1) hold same half-row
    #pragma unroll
    for (int t = 0; t < 8; ++t) {
        acc[t] += __shfl_xor(acc[t], 2, 8);
        acc[t] += __shfl_xor(acc[t], 4, 8);
    }

    const float rd = 1.f / (float)(dcnt < 1 ? 1 : dcnt);
    if (r == 0) {
        float w[8];
        #pragma unroll
        for (int t = 0; t < 8; ++t) {
            float wv = acc[t] * rd + b2[t];
            w[t] = wv > 0.f ? wv : 0.f;
        }
        *(float4*)(out + (size_t)n * ODIM)     = make_float4(w[0], w[1], w[2], w[3]);
        *(float4*)(out + (size_t)n * ODIM + 4) = make_float4(w[4], w[5], w[6], w[7]);
    } else if (r == 1) {
        float w[4];
        #pragma unroll
        for (int t = 0; t < 4; ++t) {
            float wv = acc[t] * rd + b2[8 + t];
            w[t] = wv > 0.f ? wv : 0.f;
        }
        *(float4*)(out + (size_t)n * ODIM + 8) = make_float4(w[0], w[1], w[2], w[3]);
    }
}

extern "C" void kernel_launch(void* const* d_in, const int* in_sizes, int n_in,
                              void* d_out, int out_size, void* d_ws, size_t ws_size,
                              hipStream_t stream) {
    const float* feat = (const float*)d_in[0];
    const int*   src  = (const int*)d_in[1];
    const int*   dst  = (const int*)d_in[2];
    const float* W1   = (const float*)d_in[3];
    const float* b1   = (const float*)d_in[4];
    const float* W2   = (const float*)d_in[5];
    const float* b2   = (const float*)d_in[6];
    float* out = (float*)d_out;

    const int nEdges = in_sizes[1];
    const int nNodes = in_sizes[0] / N_IN;                 // 100000
    const int nb     = (nNodes + RNODES - 1) / RNODES;     // 782
    const int hbGrid = 2 * nb;                             // 1564 half-bucket blocks

    // ws: h1[N*32] h | h2[N*16] h | bcur[NBK] i | pairs[NBMAX*BCAP] i
    __half* h1    = (__half*)d_ws;
    __half* h2    = h1 + (size_t)nNodes * HID;
    int*    bcur  = (int*)(h2 + (size_t)nNodes * H2P);
    int*    pairs = bcur + NBK;

    gemm1_kernel<<<(nNodes + 63) / 64, 256, 0, stream>>>(feat, W1, h1, bcur, nNodes);
    bplace_kernel<<<(nEdges + CHUNK - 1) / CHUNK, 512, 0, stream>>>(src, dst, bcur, pairs, nEdges);
    l1_kernel<<<hbGrid, 512, 0, stream>>>(h1, bcur, pairs, b1, W2, h2, nNodes);
    l2_kernel<<<hbGrid, 512, 0, stream>>>(h2, bcur, pairs, b2, out, nNodes);
}